// Round 4
// baseline (276.816 us; speedup 1.0000x reference)
//
#include <hip/hip_runtime.h>

#define LOG2E 1.4426950408889634f

typedef __attribute__((ext_vector_type(8))) short frag_ab;   // 8 bf16 (4 VGPRs)
typedef __attribute__((ext_vector_type(4))) float frag_cd;   // 4 fp32 acc

// fp32 -> bf16 bits, round-to-nearest-even (inputs finite)
__device__ inline short f2bf(float f) {
    union { float f; unsigned u; } v; v.f = f;
    unsigned r = v.u + 0x7fffu + ((v.u >> 16) & 1u);
    return (short)(r >> 16);
}

// x += row_ror<N>(x) on the VALU pipe (DPP), within each 16-lane row.
template<int CTRL>
__device__ inline float dpp_ror_add(float x) {
    int t = __builtin_amdgcn_update_dpp(0, __builtin_bit_cast(int, x), CTRL, 0xf, 0xf, false);
    return x + __builtin_bit_cast(float, t);
}

// async global->LDS, 16 B per lane
#define GLD_TO_LDS(gp, lp)                                                              \
    __builtin_amdgcn_global_load_lds((const __attribute__((address_space(1))) void*)(gp), \
                                     (__attribute__((address_space(3))) void*)(lp), 16, 0, 0)

// Convert W[128][1024] fp32 -> wbf bf16 in MFMA *fragment order*:
//   element (h,k): chunk c=k>>6, kstep s=(k>>5)&1, kg=(k>>3)&3, j=k&7,
//   ntile nt=h>>4, m=h&15, lane=kg*16+m
//   wbf[ (((c*8+nt)*2+s)*64 + lane)*8 + j ]
__global__ __launch_bounds__(256) void prep_kernel(const float* __restrict__ W,
                                                   short* __restrict__ wbf) {
    int g = blockIdx.x * 256 + threadIdx.x;   // 0..16383
    int h = g >> 7;
    int k0 = (g & 127) << 3;
    const float* src = W + h * 1024 + k0;
    float4 w0 = *(const float4*)src;
    float4 w1 = *(const float4*)(src + 4);
    frag_ab af;
    af[0] = f2bf(w0.x); af[1] = f2bf(w0.y); af[2] = f2bf(w0.z); af[3] = f2bf(w0.w);
    af[4] = f2bf(w1.x); af[5] = f2bf(w1.y); af[6] = f2bf(w1.z); af[7] = f2bf(w1.w);
    int c = k0 >> 6, s = (k0 >> 5) & 1, kg = (k0 >> 3) & 3;
    int nt = h >> 4, m = h & 15, lane = kg * 16 + m;
    int dst = (((c * 8 + nt) * 2 + s) * 64 + lane) * 8;
    *(frag_ab*)(wbf + dst) = af;
}

// Fused proj + softmax-combine. 64 rows (32 b's) per block, 256 threads.
// LDS = 32 KB union { phase1: Bs[2][16KB] ; phase2: vmf[16][132] + obuf[2][16][132] }
// -> 4 blocks/CU (16 waves/CU) for latency hiding in both phases.
// Phase 2 is staged: round w parks wave w's accumulator (16 rows = 8 b's) in vmf,
// all 256 threads process those 8 b's (2 per barrier pair via obuf[2]).
__global__ __launch_bounds__(256, 4) void fused_kernel(const float* __restrict__ x,
                                                       const short* __restrict__ wbf,
                                                       const float* __restrict__ cov,
                                                       const float* __restrict__ bias,
                                                       float* __restrict__ out) {
    __shared__ __align__(16) char smem[32768];

    const int tid = threadIdx.x;
    const int lane = tid & 63, wave = tid >> 6;
    const int m = lane & 15, kg = lane >> 4;
    const long rowbase = (long)blockIdx.x * 64 + wave * 16;
    const float* xrow = x + (rowbase + m) * 1024 + kg * 8;

    const float bias_own = bias[tid & 127];

    frag_cd acc[8];
#pragma unroll
    for (int nt = 0; nt < 8; ++nt) acc[nt] = (frag_cd){0.f, 0.f, 0.f, 0.f};

    // issue DMA: B chunk 0 -> buf 0
    {
        const char* wc = (const char*)wbf;
        char* bd = smem;
        GLD_TO_LDS(wc + tid * 16,         bd + tid * 16);
        GLD_TO_LDS(wc + 4096 + tid * 16,  bd + 4096 + tid * 16);
        GLD_TO_LDS(wc + 8192 + tid * 16,  bd + 8192 + tid * 16);
        GLD_TO_LDS(wc + 12288 + tid * 16, bd + 12288 + tid * 16);
    }
    // prefetch A chunk 0
    float4 a0 = *(const float4*)(xrow);
    float4 a1 = *(const float4*)(xrow + 4);
    float4 a2 = *(const float4*)(xrow + 32);
    float4 a3 = *(const float4*)(xrow + 36);
    __syncthreads();   // drains DMA -> buf0 ready

    int cb = 0;
    for (int c = 0; c < 16; ++c) {
        float4 n0, n1, n2, n3;
        if (c < 15) {
            // issue DMA: B chunk c+1 -> buf cb^1 (not read this iteration)
            const char* wc = (const char*)wbf + (c + 1) * 16384;
            char* bd = smem + (cb ^ 1) * 16384;
            GLD_TO_LDS(wc + tid * 16,         bd + tid * 16);
            GLD_TO_LDS(wc + 4096 + tid * 16,  bd + 4096 + tid * 16);
            GLD_TO_LDS(wc + 8192 + tid * 16,  bd + 8192 + tid * 16);
            GLD_TO_LDS(wc + 12288 + tid * 16, bd + 12288 + tid * 16);
            const float* xn = xrow + (c + 1) * 64;
            n0 = *(const float4*)(xn);
            n1 = *(const float4*)(xn + 4);
            n2 = *(const float4*)(xn + 32);
            n3 = *(const float4*)(xn + 36);
        }
        frag_ab af0, af1;
        af0[0] = f2bf(a0.x); af0[1] = f2bf(a0.y); af0[2] = f2bf(a0.z); af0[3] = f2bf(a0.w);
        af0[4] = f2bf(a1.x); af0[5] = f2bf(a1.y); af0[6] = f2bf(a1.z); af0[7] = f2bf(a1.w);
        af1[0] = f2bf(a2.x); af1[1] = f2bf(a2.y); af1[2] = f2bf(a2.z); af1[3] = f2bf(a2.w);
        af1[4] = f2bf(a3.x); af1[5] = f2bf(a3.y); af1[6] = f2bf(a3.z); af1[7] = f2bf(a3.w);

        const char* bs = smem + cb * 16384;
#pragma unroll
        for (int nt = 0; nt < 8; ++nt) {
            frag_ab bf0 = *(const frag_ab*)(bs + (nt * 2 + 0) * 1024 + lane * 16);
            acc[nt] = __builtin_amdgcn_mfma_f32_16x16x32_bf16(af0, bf0, acc[nt], 0, 0, 0);
            frag_ab bf1 = *(const frag_ab*)(bs + (nt * 2 + 1) * 1024 + lane * 16);
            acc[nt] = __builtin_amdgcn_mfma_f32_16x16x32_bf16(af1, bf1, acc[nt], 0, 0, 0);
        }
        if (c < 15) { a0 = n0; a1 = n1; a2 = n2; a3 = n3; }
        __syncthreads();   // drains this iter's ds_reads AND the cb^1 DMA
        cb ^= 1;
    }
    // phase-1 loop ended with __syncthreads: Bs fully consumed, safe to alias.

    // ---- phase 2 setup: cov fragment (log2e-scaled), pinned in VGPRs ----
    const int i = tid >> 4;   // h-group: h in [8i, 8i+8)
    const int j = tid & 15;   // k-group: k in [8j, 8j+8)
    float covreg[8][8];
#pragma unroll
    for (int hh = 0; hh < 8; ++hh) {
        const float* cr = cov + (long)(i * 8 + hh) * 128 + j * 8;
        float4 c0 = *(const float4*)cr;
        float4 c1 = *(const float4*)(cr + 4);
        covreg[hh][0] = LOG2E * c0.x; covreg[hh][1] = LOG2E * c0.y;
        covreg[hh][2] = LOG2E * c0.z; covreg[hh][3] = LOG2E * c0.w;
        covreg[hh][4] = LOG2E * c1.x; covreg[hh][5] = LOG2E * c1.y;
        covreg[hh][6] = LOG2E * c1.z; covreg[hh][7] = LOG2E * c1.w;
    }
#pragma unroll
    for (int hh = 0; hh < 8; ++hh)
        asm volatile("" : "+v"(covreg[hh][0]), "+v"(covreg[hh][1]), "+v"(covreg[hh][2]),
                          "+v"(covreg[hh][3]), "+v"(covreg[hh][4]), "+v"(covreg[hh][5]),
                          "+v"(covreg[hh][6]), "+v"(covreg[hh][7]));

    float* vmf  = (float*)smem;          // [16][132]
    float* obuf = vmf + 16 * 132;        // [2][16][132]
    const long outbase = (long)blockIdx.x * 32 * 128;

    for (int w = 0; w < 4; ++w) {
        // round w: wave w parks its 16 rows (8 b's) in vmf
        if (wave == w) {
#pragma unroll
            for (int nt = 0; nt < 8; ++nt)
#pragma unroll
                for (int r = 0; r < 4; ++r)
                    vmf[(kg * 4 + r) * 132 + nt * 16 + m] = acc[nt][r];
        }
        __syncthreads();   // vmf ready (prev round's obuf reads also done)

        for (int r2 = 0; r2 < 4; ++r2) {
#pragma unroll
            for (int sb = 0; sb < 2; ++sb) {
                const int lb = r2 * 2 + sb;   // local b 0..7
                // broadcast reads: all 16 lanes of a j-row read the same 32 B
                const float* vrow = vmf + (2 * lb) * 132 + i * 8;
                const float* mrow = vmf + (2 * lb + 1) * 132 + i * 8;
                float4 v0  = *(const float4*)(vrow);
                float4 v1  = *(const float4*)(vrow + 4);
                float4 mk0 = *(const float4*)(mrow);
                float4 mk1 = *(const float4*)(mrow + 4);
                float vh[8] = {v0.x, v0.y, v0.z, v0.w, v1.x, v1.y, v1.z, v1.w};
                float mh[8] = {mk0.x, mk0.y, mk0.z, mk0.w, mk1.x, mk1.y, mk1.z, mk1.w};
                float op[8] = {0.f, 0.f, 0.f, 0.f, 0.f, 0.f, 0.f, 0.f};
#pragma unroll
                for (int hh = 0; hh < 8; ++hh) {
                    float mv = mh[hh];
                    float p[8];
#pragma unroll
                    for (int kk = 0; kk < 8; ++kk)
                        p[kk] = __builtin_amdgcn_exp2f(mv * covreg[hh][kk]);
                    float s0 = p[0] + p[1], s1 = p[2] + p[3];
                    float s2 = p[4] + p[5], s3 = p[6] + p[7];
                    float lsum = (s0 + s1) + (s2 + s3);
                    lsum = dpp_ror_add<0x121>(lsum);   // row_ror:1
                    lsum = dpp_ror_add<0x122>(lsum);   // row_ror:2
                    lsum = dpp_ror_add<0x124>(lsum);   // row_ror:4
                    lsum = dpp_ror_add<0x128>(lsum);   // row_ror:8
                    float wgt = vh[hh] * __builtin_amdgcn_rcpf(lsum);
#pragma unroll
                    for (int kk = 0; kk < 8; ++kk) op[kk] = fmaf(wgt, p[kk], op[kk]);
                }
                *(float4*)(obuf + (sb * 16 + i) * 132 + j * 8)     = make_float4(op[0], op[1], op[2], op[3]);
                *(float4*)(obuf + (sb * 16 + i) * 132 + j * 8 + 4) = make_float4(op[4], op[5], op[6], op[7]);
            }
            __syncthreads();
            // 256 threads reduce 2 sub-b x 128 k: thread t -> sb = t>>7, k = t&127
            {
                const int k  = tid & 127;
                const int s0 = tid >> 7;
                float o = bias_own;
#pragma unroll
                for (int ii = 0; ii < 16; ++ii) o += obuf[(s0 * 16 + ii) * 132 + k];
                out[outbase + (w * 8 + r2 * 2 + s0) * 128 + k] = o;
            }
            __syncthreads();   // obuf free for next pair (and vmf for next round)
        }
    }
}

extern "C" void kernel_launch(void* const* d_in, const int* in_sizes, int n_in,
                              void* d_out, int out_size, void* d_ws, size_t ws_size,
                              hipStream_t stream) {
    const float* x    = (const float*)d_in[0];
    const float* W    = (const float*)d_in[1];
    const float* cov  = (const float*)d_in[2];
    const float* bias = (const float*)d_in[3];
    float* out = (float*)d_out;

    const int B = in_sizes[0] / (2 * 1024);   // 16384

    short* wbf = (short*)d_ws;                // [128*1024] bf16, fragment order

    prep_kernel<<<64, 256, 0, stream>>>(W, wbf);
    fused_kernel<<<(2 * B) / 64, 256, 0, stream>>>(x, wbf, cov, bias, out);
}

// Round 5
// 261.593 us; speedup vs baseline: 1.0582x; 1.0582x over previous
//
#include <hip/hip_runtime.h>

#define LOG2E 1.4426950408889634f

typedef __attribute__((ext_vector_type(8))) short frag_ab;   // 8 bf16 (4 VGPRs)
typedef __attribute__((ext_vector_type(4))) float frag_cd;   // 4 fp32 acc

// fp32 -> bf16 bits, round-to-nearest-even (inputs finite)
__device__ inline short f2bf(float f) {
    union { float f; unsigned u; } v; v.f = f;
    unsigned r = v.u + 0x7fffu + ((v.u >> 16) & 1u);
    return (short)(r >> 16);
}

// x += row_ror<N>(x) on the VALU pipe (DPP), within each 16-lane row.
template<int CTRL>
__device__ inline float dpp_ror_add(float x) {
    int t = __builtin_amdgcn_update_dpp(0, __builtin_bit_cast(int, x), CTRL, 0xf, 0xf, false);
    return x + __builtin_bit_cast(float, t);
}

// async global->LDS, 16 B per lane
#define GLD_TO_LDS(gp, lp)                                                              \
    __builtin_amdgcn_global_load_lds((const __attribute__((address_space(1))) void*)(gp), \
                                     (__attribute__((address_space(3))) void*)(lp), 16, 0, 0)

// pack 4+4 floats into one bf16 fragment
#define PACK_AF(af, p0, p1)                                                   \
    af[0] = f2bf(p0.x); af[1] = f2bf(p0.y); af[2] = f2bf(p0.z); af[3] = f2bf(p0.w); \
    af[4] = f2bf(p1.x); af[5] = f2bf(p1.y); af[6] = f2bf(p1.z); af[7] = f2bf(p1.w);

// Convert W[128][1024] fp32 -> wbf bf16 in MFMA *fragment order*:
//   element (h,k): chunk c=k>>6, kstep s=(k>>5)&1, kg=(k>>3)&3, j=k&7,
//   ntile nt=h>>4, m=h&15, lane=kg*16+m
//   wbf[ (((c*8+nt)*2+s)*64 + lane)*8 + j ]
__global__ __launch_bounds__(256) void prep_kernel(const float* __restrict__ W,
                                                   short* __restrict__ wbf) {
    int g = blockIdx.x * 256 + threadIdx.x;   // 0..16383
    int h = g >> 7;
    int k0 = (g & 127) << 3;
    const float* src = W + h * 1024 + k0;
    float4 w0 = *(const float4*)src;
    float4 w1 = *(const float4*)(src + 4);
    frag_ab af;
    PACK_AF(af, w0, w1);
    int c = k0 >> 6, s = (k0 >> 5) & 1, kg = (k0 >> 3) & 3;
    int nt = h >> 4, m = h & 15, lane = kg * 16 + m;
    int dst = (((c * 8 + nt) * 2 + s) * 64 + lane) * 8;
    *(frag_ab*)(wbf + dst) = af;
}

// proj: vm[row][h] = sum_k x[row][k]*W[h][k]. 64 rows per block, 512 blocks.
// B staged via global_load_lds double-buffer (L2-hot after first blocks).
// A (x, HBM) prefetched TWO chunks deep in registers (even/odd slots) so the
// ~900-cycle HBM latency is covered by two compute+barrier windows.
__global__ __launch_bounds__(256, 2) void proj_kernel(const float* __restrict__ x,
                                                      const short* __restrict__ wbf,
                                                      float* __restrict__ vm) {
    __shared__ __align__(16) char smem[32768];   // Bs[2][16 KB]

    const int tid = threadIdx.x;
    const int lane = tid & 63, wave = tid >> 6;
    const int m = lane & 15, kg = lane >> 4;
    const long rowbase = (long)blockIdx.x * 64 + wave * 16;
    const float* xrow = x + (rowbase + m) * 1024 + kg * 8;

    frag_cd acc[8];
#pragma unroll
    for (int nt = 0; nt < 8; ++nt) acc[nt] = (frag_cd){0.f, 0.f, 0.f, 0.f};

    // DMA: B chunk 0 -> buf 0
    {
        const char* wc = (const char*)wbf;
        GLD_TO_LDS(wc + tid * 16,         smem + tid * 16);
        GLD_TO_LDS(wc + 4096 + tid * 16,  smem + 4096 + tid * 16);
        GLD_TO_LDS(wc + 8192 + tid * 16,  smem + 8192 + tid * 16);
        GLD_TO_LDS(wc + 12288 + tid * 16, smem + 12288 + tid * 16);
    }
    // A prefetch: chunk 0 -> slot A, chunk 1 -> slot B (2-deep)
    float4 aA0 = *(const float4*)(xrow);
    float4 aA1 = *(const float4*)(xrow + 4);
    float4 aA2 = *(const float4*)(xrow + 32);
    float4 aA3 = *(const float4*)(xrow + 36);
    float4 aB0 = *(const float4*)(xrow + 64);
    float4 aB1 = *(const float4*)(xrow + 68);
    float4 aB2 = *(const float4*)(xrow + 96);
    float4 aB3 = *(const float4*)(xrow + 100);
    __syncthreads();   // buf0 ready

    int cb = 0;
#pragma unroll
    for (int cc = 0; cc < 8; ++cc) {
        const int c0 = 2 * cc, c1 = 2 * cc + 1;
        // ---- even chunk c0 (A slot A) ----
        {
            // DMA next B (c0+1 <= 15 always)
            const char* wc = (const char*)wbf + (c0 + 1) * 16384;
            char* bd = smem + (cb ^ 1) * 16384;
            GLD_TO_LDS(wc + tid * 16,         bd + tid * 16);
            GLD_TO_LDS(wc + 4096 + tid * 16,  bd + 4096 + tid * 16);
            GLD_TO_LDS(wc + 8192 + tid * 16,  bd + 8192 + tid * 16);
            GLD_TO_LDS(wc + 12288 + tid * 16, bd + 12288 + tid * 16);

            frag_ab af0, af1;
            PACK_AF(af0, aA0, aA1);
            PACK_AF(af1, aA2, aA3);
            if (c0 + 2 < 16) {   // refill slot A two chunks ahead
                const float* xn = xrow + (c0 + 2) * 64;
                aA0 = *(const float4*)(xn);
                aA1 = *(const float4*)(xn + 4);
                aA2 = *(const float4*)(xn + 32);
                aA3 = *(const float4*)(xn + 36);
            }
            const char* bs = smem + cb * 16384;
#pragma unroll
            for (int nt = 0; nt < 8; ++nt) {
                frag_ab bf0 = *(const frag_ab*)(bs + (nt * 2 + 0) * 1024 + lane * 16);
                acc[nt] = __builtin_amdgcn_mfma_f32_16x16x32_bf16(af0, bf0, acc[nt], 0, 0, 0);
                frag_ab bf1 = *(const frag_ab*)(bs + (nt * 2 + 1) * 1024 + lane * 16);
                acc[nt] = __builtin_amdgcn_mfma_f32_16x16x32_bf16(af1, bf1, acc[nt], 0, 0, 0);
            }
            __syncthreads();
            cb ^= 1;
        }
        // ---- odd chunk c1 (A slot B) ----
        {
            if (c1 < 15) {
                const char* wc = (const char*)wbf + (c1 + 1) * 16384;
                char* bd = smem + (cb ^ 1) * 16384;
                GLD_TO_LDS(wc + tid * 16,         bd + tid * 16);
                GLD_TO_LDS(wc + 4096 + tid * 16,  bd + 4096 + tid * 16);
                GLD_TO_LDS(wc + 8192 + tid * 16,  bd + 8192 + tid * 16);
                GLD_TO_LDS(wc + 12288 + tid * 16, bd + 12288 + tid * 16);
            }
            frag_ab af0, af1;
            PACK_AF(af0, aB0, aB1);
            PACK_AF(af1, aB2, aB3);
            if (c1 + 2 < 16) {   // refill slot B two chunks ahead
                const float* xn = xrow + (c1 + 2) * 64;
                aB0 = *(const float4*)(xn);
                aB1 = *(const float4*)(xn + 4);
                aB2 = *(const float4*)(xn + 32);
                aB3 = *(const float4*)(xn + 36);
            }
            const char* bs = smem + cb * 16384;
#pragma unroll
            for (int nt = 0; nt < 8; ++nt) {
                frag_ab bf0 = *(const frag_ab*)(bs + (nt * 2 + 0) * 1024 + lane * 16);
                acc[nt] = __builtin_amdgcn_mfma_f32_16x16x32_bf16(af0, bf0, acc[nt], 0, 0, 0);
                frag_ab bf1 = *(const frag_ab*)(bs + (nt * 2 + 1) * 1024 + lane * 16);
                acc[nt] = __builtin_amdgcn_mfma_f32_16x16x32_bf16(af1, bf1, acc[nt], 0, 0, 0);
            }
            __syncthreads();
            cb ^= 1;
        }
    }

    // C/D: col = lane&15 (=h within tile), row = kg*4 + r
#pragma unroll
    for (int nt = 0; nt < 8; ++nt)
#pragma unroll
        for (int r = 0; r < 4; ++r) {
            long row = rowbase + kg * 4 + r;
            vm[row * 128 + nt * 16 + m] = acc[nt][r];
        }
}

// combine: out[b,k] = bias[k] + sum_h (v[b,h]/l[b,h]) * exp2(log2e*mask[b,h]*cov[h,k])
// 2048 blocks x 256 threads (4 blocks/CU, 16 waves/CU). 8 b's per block.
// Thread (i=t>>4, j=t&15) owns h in [8i,8i+8), k in [8j,8j+8); cov tile in VGPRs.
// lsum via DPP row_ror chain (VALU pipe); h-reduction via obuf, 2 b's per barrier pair.
__global__ __launch_bounds__(256, 4) void combine_kernel(const float* __restrict__ vm,
                                                         const float* __restrict__ cov,
                                                         const float* __restrict__ bias,
                                                         float* __restrict__ out) {
    __shared__ float obuf[2][16][132];

    const int tid = threadIdx.x;
    const int i = tid >> 4;   // h-group
    const int j = tid & 15;   // k-group
    const float bias_own = bias[tid & 127];

    float covreg[8][8];
#pragma unroll
    for (int hh = 0; hh < 8; ++hh) {
        const float* cr = cov + (long)(i * 8 + hh) * 128 + j * 8;
        float4 c0 = *(const float4*)cr;
        float4 c1 = *(const float4*)(cr + 4);
        covreg[hh][0] = LOG2E * c0.x; covreg[hh][1] = LOG2E * c0.y;
        covreg[hh][2] = LOG2E * c0.z; covreg[hh][3] = LOG2E * c0.w;
        covreg[hh][4] = LOG2E * c1.x; covreg[hh][5] = LOG2E * c1.y;
        covreg[hh][6] = LOG2E * c1.z; covreg[hh][7] = LOG2E * c1.w;
    }
#pragma unroll
    for (int hh = 0; hh < 8; ++hh)
        asm volatile("" : "+v"(covreg[hh][0]), "+v"(covreg[hh][1]), "+v"(covreg[hh][2]),
                          "+v"(covreg[hh][3]), "+v"(covreg[hh][4]), "+v"(covreg[hh][5]),
                          "+v"(covreg[hh][6]), "+v"(covreg[hh][7]));

    const long b0 = (long)blockIdx.x * 8;
    for (int rr = 0; rr < 4; ++rr) {
#pragma unroll
        for (int sb = 0; sb < 2; ++sb) {
            const long b = b0 + rr * 2 + sb;
            // broadcast: all 16 lanes of a j-row read the same 32 B (L1/L2-hot vm)
            const float* vrow = vm + (2 * b) * 128 + i * 8;
            const float* mrow = vm + (2 * b + 1) * 128 + i * 8;
            float4 v0  = *(const float4*)(vrow);
            float4 v1  = *(const float4*)(vrow + 4);
            float4 mk0 = *(const float4*)(mrow);
            float4 mk1 = *(const float4*)(mrow + 4);
            float vh[8] = {v0.x, v0.y, v0.z, v0.w, v1.x, v1.y, v1.z, v1.w};
            float mh[8] = {mk0.x, mk0.y, mk0.z, mk0.w, mk1.x, mk1.y, mk1.z, mk1.w};
            float op[8] = {0.f, 0.f, 0.f, 0.f, 0.f, 0.f, 0.f, 0.f};
#pragma unroll
            for (int hh = 0; hh < 8; ++hh) {
                float mv = mh[hh];
                float p[8];
#pragma unroll
                for (int kk = 0; kk < 8; ++kk)
                    p[kk] = __builtin_amdgcn_exp2f(mv * covreg[hh][kk]);
                float s0 = p[0] + p[1], s1 = p[2] + p[3];
                float s2 = p[4] + p[5], s3 = p[6] + p[7];
                float lsum = (s0 + s1) + (s2 + s3);
                lsum = dpp_ror_add<0x121>(lsum);   // row_ror:1
                lsum = dpp_ror_add<0x122>(lsum);   // row_ror:2
                lsum = dpp_ror_add<0x124>(lsum);   // row_ror:4
                lsum = dpp_ror_add<0x128>(lsum);   // row_ror:8
                float w = vh[hh] * __builtin_amdgcn_rcpf(lsum);
#pragma unroll
                for (int kk = 0; kk < 8; ++kk) op[kk] = fmaf(w, p[kk], op[kk]);
            }
            *(float4*)&obuf[sb][i][j * 8]     = make_float4(op[0], op[1], op[2], op[3]);
            *(float4*)&obuf[sb][i][j * 8 + 4] = make_float4(op[4], op[5], op[6], op[7]);
        }
        __syncthreads();
        // 256 threads reduce 2 sub-b x 128 k
        {
            const int k  = tid & 127;
            const int s0 = tid >> 7;
            float o = bias_own;
#pragma unroll
            for (int ii = 0; ii < 16; ++ii) o += obuf[s0][ii][k];
            out[(b0 + rr * 2 + s0) * 128 + k] = o;
        }
        __syncthreads();
    }
}

extern "C" void kernel_launch(void* const* d_in, const int* in_sizes, int n_in,
                              void* d_out, int out_size, void* d_ws, size_t ws_size,
                              hipStream_t stream) {
    const float* x    = (const float*)d_in[0];
    const float* W    = (const float*)d_in[1];
    const float* cov  = (const float*)d_in[2];
    const float* bias = (const float*)d_in[3];
    float* out = (float*)d_out;

    const int B = in_sizes[0] / (2 * 1024);   // 16384

    short* wbf = (short*)d_ws;                          // [128*1024] bf16, frag order
    float* vm  = (float*)(wbf + 128 * 1024);            // [2B][128] fp32

    prep_kernel<<<64, 256, 0, stream>>>(W, wbf);
    proj_kernel<<<(2 * B) / 64, 256, 0, stream>>>(x, wbf, vm);
    combine_kernel<<<B / 8, 256, 0, stream>>>(vm, cov, bias, out);
}

// Round 6
// 255.340 us; speedup vs baseline: 1.0841x; 1.0245x over previous
//
#include <hip/hip_runtime.h>

#define LOG2E 1.4426950408889634f

typedef __attribute__((ext_vector_type(8))) short frag_ab;   // 8 bf16 (4 VGPRs)
typedef __attribute__((ext_vector_type(4))) float frag_cd;   // 4 fp32 acc

// fp32 -> bf16 bits, round-to-nearest-even (inputs finite)
__device__ inline short f2bf(float f) {
    union { float f; unsigned u; } v; v.f = f;
    unsigned r = v.u + 0x7fffu + ((v.u >> 16) & 1u);
    return (short)(r >> 16);
}

// x += row_ror<N>(x) on the VALU pipe (DPP), within each 16-lane row.
template<int CTRL>
__device__ inline float dpp_ror_add(float x) {
    int t = __builtin_amdgcn_update_dpp(0, __builtin_bit_cast(int, x), CTRL, 0xf, 0xf, false);
    return x + __builtin_bit_cast(float, t);
}

// async global->LDS, 16 B per lane
#define GLD_TO_LDS(gp, lp)                                                              \
    __builtin_amdgcn_global_load_lds((const __attribute__((address_space(1))) void*)(gp), \
                                     (__attribute__((address_space(3))) void*)(lp), 16, 0, 0)

// pack 4+4 floats into one bf16 fragment
#define PACK_AF(af, p0, p1)                                                   \
    af[0] = f2bf(p0.x); af[1] = f2bf(p0.y); af[2] = f2bf(p0.z); af[3] = f2bf(p0.w); \
    af[4] = f2bf(p1.x); af[5] = f2bf(p1.y); af[6] = f2bf(p1.z); af[7] = f2bf(p1.w);

// Convert W[128][1024] fp32 -> wbf bf16 in MFMA *fragment order*:
//   element (h,k): chunk c=k>>6, kstep s=(k>>5)&1, kg=(k>>3)&3, j=k&7,
//   ntile nt=h>>4, m=h&15, lane=kg*16+m
//   wbf[ (((c*8+nt)*2+s)*64 + lane)*8 + j ]
__global__ __launch_bounds__(256) void prep_kernel(const float* __restrict__ W,
                                                   short* __restrict__ wbf) {
    int g = blockIdx.x * 256 + threadIdx.x;   // 0..16383
    int h = g >> 7;
    int k0 = (g & 127) << 3;
    const float* src = W + h * 1024 + k0;
    float4 w0 = *(const float4*)src;
    float4 w1 = *(const float4*)(src + 4);
    frag_ab af;
    PACK_AF(af, w0, w1);
    int c = k0 >> 6, s = (k0 >> 5) & 1, kg = (k0 >> 3) & 3;
    int nt = h >> 4, m = h & 15, lane = kg * 16 + m;
    int dst = (((c * 8 + nt) * 2 + s) * 64 + lane) * 8;
    *(frag_ab*)(wbf + dst) = af;
}

// proj: vm[row][h] = sum_k x[row][k]*W[h][k]. 64 rows per block, 512 blocks.
// B staged via global_load_lds double-buffer (L2-hot), A prefetched 1-deep in regs
// (issued before the MFMA window; the pre-barrier vmcnt drain is where they land).
__global__ __launch_bounds__(256, 2) void proj_kernel(const float* __restrict__ x,
                                                      const short* __restrict__ wbf,
                                                      float* __restrict__ vm) {
    __shared__ __align__(16) char smem[32768];   // Bs[2][16 KB]

    const int tid = threadIdx.x;
    const int lane = tid & 63, wave = tid >> 6;
    const int m = lane & 15, kg = lane >> 4;
    const long rowbase = (long)blockIdx.x * 64 + wave * 16;
    const float* xrow = x + (rowbase + m) * 1024 + kg * 8;

    frag_cd acc[8];
#pragma unroll
    for (int nt = 0; nt < 8; ++nt) acc[nt] = (frag_cd){0.f, 0.f, 0.f, 0.f};

    // DMA: B chunk 0 -> buf 0
    {
        const char* wc = (const char*)wbf;
        GLD_TO_LDS(wc + tid * 16,         smem + tid * 16);
        GLD_TO_LDS(wc + 4096 + tid * 16,  smem + 4096 + tid * 16);
        GLD_TO_LDS(wc + 8192 + tid * 16,  smem + 8192 + tid * 16);
        GLD_TO_LDS(wc + 12288 + tid * 16, smem + 12288 + tid * 16);
    }
    // prefetch A chunk 0
    float4 a0 = *(const float4*)(xrow);
    float4 a1 = *(const float4*)(xrow + 4);
    float4 a2 = *(const float4*)(xrow + 32);
    float4 a3 = *(const float4*)(xrow + 36);
    __syncthreads();   // buf0 ready

    int cb = 0;
    for (int c = 0; c < 16; ++c) {
        float4 n0, n1, n2, n3;
        if (c < 15) {
            // DMA next B -> other buffer (not read this iteration)
            const char* wc = (const char*)wbf + (c + 1) * 16384;
            char* bd = smem + (cb ^ 1) * 16384;
            GLD_TO_LDS(wc + tid * 16,         bd + tid * 16);
            GLD_TO_LDS(wc + 4096 + tid * 16,  bd + 4096 + tid * 16);
            GLD_TO_LDS(wc + 8192 + tid * 16,  bd + 8192 + tid * 16);
            GLD_TO_LDS(wc + 12288 + tid * 16, bd + 12288 + tid * 16);
            // prefetch next A (lands during MFMA window / barrier drain)
            const float* xn = xrow + (c + 1) * 64;
            n0 = *(const float4*)(xn);
            n1 = *(const float4*)(xn + 4);
            n2 = *(const float4*)(xn + 32);
            n3 = *(const float4*)(xn + 36);
        }
        frag_ab af0, af1;
        PACK_AF(af0, a0, a1);
        PACK_AF(af1, a2, a3);

        const char* bs = smem + cb * 16384;
#pragma unroll
        for (int nt = 0; nt < 8; ++nt) {
            frag_ab bf0 = *(const frag_ab*)(bs + (nt * 2 + 0) * 1024 + lane * 16);
            acc[nt] = __builtin_amdgcn_mfma_f32_16x16x32_bf16(af0, bf0, acc[nt], 0, 0, 0);
            frag_ab bf1 = *(const frag_ab*)(bs + (nt * 2 + 1) * 1024 + lane * 16);
            acc[nt] = __builtin_amdgcn_mfma_f32_16x16x32_bf16(af1, bf1, acc[nt], 0, 0, 0);
        }
        if (c < 15) { a0 = n0; a1 = n1; a2 = n2; a3 = n3; }
        __syncthreads();
        cb ^= 1;
    }

    // C/D: col = lane&15 (=h within tile), row = kg*4 + r
#pragma unroll
    for (int nt = 0; nt < 8; ++nt)
#pragma unroll
        for (int r = 0; r < 4; ++r) {
            long row = rowbase + kg * 4 + r;
            vm[row * 128 + nt * 16 + m] = acc[nt][r];
        }
}

// combine: out[b,k] = bias[k] + sum_h (v[b,h]/l[b,h]) * exp2(log2e*mask[b,h]*cov[h,k])
// 2048 blocks x 512 threads (2 blocks/CU, 16 waves/CU). 8 b's per block.
// Thread (i=t>>4 in 0..31, j=t&15) owns h in [4i,4i+4), k in [8j,8j+8).
// covreg[4][8] = 32 VGPRs (NO asm pin, small enough to never spill).
// lsum via DPP row_ror chain (VALU pipe). 4 b's per barrier round via obuf[4].
__global__ __launch_bounds__(512, 4) void combine_kernel(const float* __restrict__ vm,
                                                         const float* __restrict__ cov,
                                                         const float* __restrict__ bias,
                                                         float* __restrict__ out) {
    __shared__ float obuf[4][32][132];   // 67.6 KB

    const int t = threadIdx.x;
    const int i = t >> 4;   // h-group 0..31
    const int j = t & 15;   // k-group 0..15
    const float bias_own = bias[t & 127];

    float covreg[4][8];
#pragma unroll
    for (int hh = 0; hh < 4; ++hh) {
        const float* cr = cov + (long)(i * 4 + hh) * 128 + j * 8;
        float4 c0 = *(const float4*)cr;
        float4 c1 = *(const float4*)(cr + 4);
        covreg[hh][0] = LOG2E * c0.x; covreg[hh][1] = LOG2E * c0.y;
        covreg[hh][2] = LOG2E * c0.z; covreg[hh][3] = LOG2E * c0.w;
        covreg[hh][4] = LOG2E * c1.x; covreg[hh][5] = LOG2E * c1.y;
        covreg[hh][6] = LOG2E * c1.z; covreg[hh][7] = LOG2E * c1.w;
    }

    const long b0 = (long)blockIdx.x * 8;
    for (int rr = 0; rr < 2; ++rr) {
#pragma unroll
        for (int sb = 0; sb < 4; ++sb) {
            const long b = b0 + rr * 4 + sb;
            // broadcast: all 16 lanes of a j-row read the same 16 B (cache-hot vm)
            float4 v4 = *(const float4*)(vm + (2 * b) * 128 + i * 4);
            float4 m4 = *(const float4*)(vm + (2 * b + 1) * 128 + i * 4);
            float vh[4] = {v4.x, v4.y, v4.z, v4.w};
            float mh[4] = {m4.x, m4.y, m4.z, m4.w};
            float op[8] = {0.f, 0.f, 0.f, 0.f, 0.f, 0.f, 0.f, 0.f};
#pragma unroll
            for (int hh = 0; hh < 4; ++hh) {
                float mv = mh[hh];
                float p[8];
#pragma unroll
                for (int kk = 0; kk < 8; ++kk)
                    p[kk] = __builtin_amdgcn_exp2f(mv * covreg[hh][kk]);
                float s0 = p[0] + p[1], s1 = p[2] + p[3];
                float s2 = p[4] + p[5], s3 = p[6] + p[7];
                float lsum = (s0 + s1) + (s2 + s3);
                lsum = dpp_ror_add<0x121>(lsum);   // row_ror:1
                lsum = dpp_ror_add<0x122>(lsum);   // row_ror:2
                lsum = dpp_ror_add<0x124>(lsum);   // row_ror:4
                lsum = dpp_ror_add<0x128>(lsum);   // row_ror:8
                float w = vh[hh] * __builtin_amdgcn_rcpf(lsum);
#pragma unroll
                for (int kk = 0; kk < 8; ++kk) op[kk] = fmaf(w, p[kk], op[kk]);
            }
            *(float4*)&obuf[sb][i][j * 8]     = make_float4(op[0], op[1], op[2], op[3]);
            *(float4*)&obuf[sb][i][j * 8 + 4] = make_float4(op[4], op[5], op[6], op[7]);
        }
        __syncthreads();
        // 512 threads reduce 4 sub-b x 128 k: thread t -> sb = t>>7, k = t&127
        {
            const int k  = t & 127;
            const int sb = t >> 7;
            float o = bias_own;
#pragma unroll
            for (int ii = 0; ii < 32; ++ii) o += obuf[sb][ii][k];
            out[(b0 + rr * 4 + sb) * 128 + k] = o;
        }
        __syncthreads();
    }
}

extern "C" void kernel_launch(void* const* d_in, const int* in_sizes, int n_in,
                              void* d_out, int out_size, void* d_ws, size_t ws_size,
                              hipStream_t stream) {
    const float* x    = (const float*)d_in[0];
    const float* W    = (const float*)d_in[1];
    const float* cov  = (const float*)d_in[2];
    const float* bias = (const float*)d_in[3];
    float* out = (float*)d_out;

    const int B = in_sizes[0] / (2 * 1024);   // 16384

    short* wbf = (short*)d_ws;                          // [128*1024] bf16, frag order
    float* vm  = (float*)(wbf + 128 * 1024);            // [2B][128] fp32

    prep_kernel<<<64, 256, 0, stream>>>(W, wbf);
    proj_kernel<<<(2 * B) / 64, 256, 0, stream>>>(x, wbf, vm);
    combine_kernel<<<B / 8, 512, 0, stream>>>(vm, cov, bias, out);
}